// Round 2
// baseline (908.397 us; speedup 1.0000x reference)
//
#include <hip/hip_runtime.h>
#include <hip/hip_bf16.h>
#include <stdint.h>

#define N_TOK 8192
#define DIM   1024
#define NEXP  8
#define HID   4096
#define PADROWS 9216   // 8192 + 8*128 slack for per-expert 128-row padding

typedef unsigned short u16;
typedef __attribute__((ext_vector_type(8))) short bf16x8;
typedef __attribute__((ext_vector_type(4))) float f32x4;

__device__ inline u16 f2bf(float f) {
  union { float f; uint32_t u; } v; v.f = f;
  uint32_t r = v.u + 0x7fffu + ((v.u >> 16) & 1u);
  return (u16)(r >> 16);
}

__device__ inline void gld_lds16(const void* g, void* lds) {
  __builtin_amdgcn_global_load_lds(
      (const __attribute__((address_space(1))) uint32_t*)g,
      (__attribute__((address_space(3))) uint32_t*)lds, 16, 0, 0);
}

// ---------------- small kernels ----------------

__global__ void zero_kernel(int* counts) {
  if (threadIdx.x < NEXP) counts[threadIdx.x] = 0;
}

// one wave per token: fp32 gate logits + first-max argmax (matches np.argmax)
__global__ void gate_kernel(const float* __restrict__ x,
                            const float* __restrict__ gw,
                            const float* __restrict__ gb,
                            int* __restrict__ expert_id,
                            int* __restrict__ counts) {
  int wave = threadIdx.x >> 6;
  int lane = threadIdx.x & 63;
  int n = blockIdx.x * 4 + wave;
  const float* xr = x + (size_t)n * DIM;
  float acc[8];
#pragma unroll
  for (int e = 0; e < 8; ++e) acc[e] = 0.f;
  for (int d = lane; d < DIM; d += 64) {
    float xv = xr[d];
    const float4 g0 = *(const float4*)&gw[d * 8];
    const float4 g1 = *(const float4*)&gw[d * 8 + 4];
    acc[0] += xv * g0.x; acc[1] += xv * g0.y;
    acc[2] += xv * g0.z; acc[3] += xv * g0.w;
    acc[4] += xv * g1.x; acc[5] += xv * g1.y;
    acc[6] += xv * g1.z; acc[7] += xv * g1.w;
  }
#pragma unroll
  for (int e = 0; e < 8; ++e)
    for (int off = 32; off > 0; off >>= 1)
      acc[e] += __shfl_xor(acc[e], off);
  if (lane == 0) {
    float best = acc[0] + gb[0];
    int bi = 0;
#pragma unroll
    for (int e = 1; e < 8; ++e) {
      float v = acc[e] + gb[e];
      if (v > best) { best = v; bi = e; }
    }
    expert_id[n] = bi;
    atomicAdd(&counts[bi], 1);
  }
}

__global__ void scan_kernel(const int* __restrict__ counts,
                            int* __restrict__ offs,
                            int* __restrict__ cursor) {
  if (threadIdx.x == 0) {
    int o = 0;
    for (int e = 0; e < NEXP; ++e) {
      offs[e] = o;
      o += (counts[e] + 127) & ~127;  // 128-pad each segment
      cursor[e] = 0;
    }
    offs[NEXP] = o;
  }
}

// per-token: claim permuted slot, gather + convert row to bf16
__global__ void gather_kernel(const float* __restrict__ x,
                              const int* __restrict__ expert_id,
                              const int* __restrict__ offs,
                              int* __restrict__ cursor,
                              int* __restrict__ perm,
                              u16* __restrict__ xg) {
  int n = blockIdx.x;
  __shared__ int spos;
  if (threadIdx.x == 0) {
    int e = expert_id[n];
    int p = offs[e] + atomicAdd(&cursor[e], 1);
    perm[p] = n;
    spos = p;
  }
  __syncthreads();
  int pos = spos;
  int i = threadIdx.x * 4;
  const float4 v = *(const float4*)&x[(size_t)n * DIM + i];
  ushort4 o;
  o.x = f2bf(v.x); o.y = f2bf(v.y); o.z = f2bf(v.z); o.w = f2bf(v.w);
  *(ushort4*)&xg[(size_t)pos * DIM + i] = o;
}

// src: [E][K][Nc] fp32  ->  dst: [E][Nc][K] bf16 (transposed, MFMA B layout)
__global__ void wconv_kernel(const float* __restrict__ src,
                             u16* __restrict__ dst, int K, int Nc) {
  int e = blockIdx.z;
  int kb = blockIdx.x * 64;
  int nb = blockIdx.y * 64;
  const float* s = src + (size_t)e * K * Nc;
  u16* d = dst + (size_t)e * K * Nc;
  __shared__ u16 tile[64][66];
  int rr = threadIdx.x >> 4;
  int cc = (threadIdx.x & 15) * 4;
#pragma unroll
  for (int p = 0; p < 4; ++p) {
    int row = p * 16 + rr;
    const float4 v = *(const float4*)&s[(size_t)(kb + row) * Nc + nb + cc];
    tile[row][cc + 0] = f2bf(v.x);
    tile[row][cc + 1] = f2bf(v.y);
    tile[row][cc + 2] = f2bf(v.z);
    tile[row][cc + 3] = f2bf(v.w);
  }
  __syncthreads();
#pragma unroll
  for (int p = 0; p < 4; ++p) {
    int n = p * 16 + rr;  // dst row (src col)
    ushort4 o;
    o.x = tile[cc + 0][n];
    o.y = tile[cc + 1][n];
    o.z = tile[cc + 2][n];
    o.w = tile[cc + 3][n];
    *(ushort4*)&d[(size_t)(nb + n) * K + kb + cc] = o;
  }
}

// ---------------- GEMM core (m97 structure: 128x128 tile, BK=64, 4 waves) ----------------

__device__ inline void gemm_core(const u16* __restrict__ Abase,
                                 const u16* __restrict__ Bbase,
                                 int K, f32x4 acc[4][4],
                                 u16* As, u16* Bs) {
  const int tid = threadIdx.x;
  const int wave = tid >> 6, lane = tid & 63;
  const int wr = (wave >> 1) * 64, wc = (wave & 1) * 64;
  const int l15 = lane & 15, l4 = lane >> 4;
  const int srow = lane >> 3;          // staging: 8 lanes per row
  const int scol = (lane & 7) * 8;     // 8 bf16 = 16B per lane

  for (int kt = 0; kt < K; kt += 64) {
#pragma unroll
    for (int j = 0; j < 4; ++j) {
      int r0 = j * 32 + wave * 8;
      int row = r0 + srow;
      gld_lds16(Abase + (size_t)row * K + kt + scol, &As[r0 * 64]);
      gld_lds16(Bbase + (size_t)row * K + kt + scol, &Bs[r0 * 64]);
    }
    __syncthreads();
#pragma unroll
    for (int ks = 0; ks < 2; ++ks) {
      bf16x8 a[4], b[4];
#pragma unroll
      for (int i = 0; i < 4; ++i)
        a[i] = *(const bf16x8*)&As[(wr + i * 16 + l15) * 64 + ks * 32 + l4 * 8];
#pragma unroll
      for (int i = 0; i < 4; ++i)
        b[i] = *(const bf16x8*)&Bs[(wc + i * 16 + l15) * 64 + ks * 32 + l4 * 8];
#pragma unroll
      for (int mi = 0; mi < 4; ++mi)
#pragma unroll
        for (int ni = 0; ni < 4; ++ni)
          acc[mi][ni] = __builtin_amdgcn_mfma_f32_16x16x32_bf16(
              a[mi], b[ni], acc[mi][ni], 0, 0, 0);
    }
    __syncthreads();
  }
}

// h = relu(Xe @ w1[e] + b1[e])  -> bf16
__global__ __launch_bounds__(256) void gemm1_kernel(
    const u16* __restrict__ xg, const u16* __restrict__ w1b,
    const float* __restrict__ b1, const int* __restrict__ counts,
    const int* __restrict__ offs, u16* __restrict__ h) {
  int e = blockIdx.z, mt = blockIdx.y, nt = blockIdx.x;
  int ne = counts[e];
  if (mt * 128 >= ne) return;
  int seg = offs[e];
  __shared__ __align__(16) u16 As[128 * 64];
  __shared__ __align__(16) u16 Bs[128 * 64];
  f32x4 acc[4][4];
#pragma unroll
  for (int i = 0; i < 4; ++i)
#pragma unroll
    for (int j = 0; j < 4; ++j) acc[i][j] = (f32x4){0.f, 0.f, 0.f, 0.f};

  const u16* Abase = xg + (size_t)(seg + mt * 128) * DIM;
  const u16* Bbase = w1b + ((size_t)e * HID + nt * 128) * DIM;
  gemm_core(Abase, Bbase, DIM, acc, As, Bs);

  const int tid = threadIdx.x;
  const int wave = tid >> 6, lane = tid & 63;
  const int wr = (wave >> 1) * 64, wc = (wave & 1) * 64;
  const int l15 = lane & 15, l4 = lane >> 4;
  const int rowlim = ne - mt * 128;
  const size_t hrow0 = (size_t)(seg + mt * 128);
#pragma unroll
  for (int mi = 0; mi < 4; ++mi)
#pragma unroll
    for (int j = 0; j < 4; ++j) {
      int r = wr + mi * 16 + l4 * 4 + j;
      if (r < rowlim) {
        u16* hp = h + (hrow0 + r) * (size_t)HID;
#pragma unroll
        for (int ni = 0; ni < 4; ++ni) {
          int c = nt * 128 + wc + ni * 16 + l15;
          float v = acc[mi][ni][j] + b1[e * HID + c];
          hp[c] = f2bf(fmaxf(v, 0.f));
        }
      }
    }
}

// out[perm] = h @ w2[e] + b2[e] + x[perm]   (fp32 out)
__global__ __launch_bounds__(256) void gemm2_kernel(
    const u16* __restrict__ h, const u16* __restrict__ w2b,
    const float* __restrict__ b2, const float* __restrict__ x,
    const int* __restrict__ counts, const int* __restrict__ offs,
    const int* __restrict__ perm, float* __restrict__ out) {
  int e = blockIdx.z, mt = blockIdx.y, nt = blockIdx.x;
  int ne = counts[e];
  if (mt * 128 >= ne) return;
  int seg = offs[e];
  __shared__ __align__(16) u16 As[128 * 64];
  __shared__ __align__(16) u16 Bs[128 * 64];
  f32x4 acc[4][4];
#pragma unroll
  for (int i = 0; i < 4; ++i)
#pragma unroll
    for (int j = 0; j < 4; ++j) acc[i][j] = (f32x4){0.f, 0.f, 0.f, 0.f};

  const u16* Abase = h + (size_t)(seg + mt * 128) * HID;
  const u16* Bbase = w2b + ((size_t)e * DIM + nt * 128) * HID;
  gemm_core(Abase, Bbase, HID, acc, As, Bs);

  const int tid = threadIdx.x;
  const int wave = tid >> 6, lane = tid & 63;
  const int wr = (wave >> 1) * 64, wc = (wave & 1) * 64;
  const int l15 = lane & 15, l4 = lane >> 4;
  const int rowlim = ne - mt * 128;
  const int prow0 = seg + mt * 128;
#pragma unroll
  for (int mi = 0; mi < 4; ++mi)
#pragma unroll
    for (int j = 0; j < 4; ++j) {
      int r = wr + mi * 16 + l4 * 4 + j;
      if (r < rowlim) {
        int orig = perm[prow0 + r];
        const float* xr = x + (size_t)orig * DIM;
        float* op = out + (size_t)orig * DIM;
#pragma unroll
        for (int ni = 0; ni < 4; ++ni) {
          int c = nt * 128 + wc + ni * 16 + l15;
          op[c] = acc[mi][ni][j] + b2[e * DIM + c] + xr[c];
        }
      }
    }
}

// ---------------- launch ----------------

extern "C" void kernel_launch(void* const* d_in, const int* in_sizes, int n_in,
                              void* d_out, int out_size, void* d_ws, size_t ws_size,
                              hipStream_t stream) {
  const float* x  = (const float*)d_in[0];
  const float* gw = (const float*)d_in[1];
  const float* gb = (const float*)d_in[2];
  const float* w1 = (const float*)d_in[3];
  const float* b1 = (const float*)d_in[4];
  const float* w2 = (const float*)d_in[5];
  const float* b2 = (const float*)d_in[6];
  float* out = (float*)d_out;

  char* ws = (char*)d_ws;
  int* counts    = (int*)(ws + 0);
  int* offs      = (int*)(ws + 64);
  int* cursor    = (int*)(ws + 128);
  int* expert_id = (int*)(ws + 256);            // 32 KB
  int* perm      = (int*)(ws + 33280);          // 36 KB
  u16* xg  = (u16*)(ws + (size_t)131072);       // 9216*1024*2  = 18.0 MB
  u16* h   = (u16*)(ws + (size_t)0x1400000);    // 9216*4096*2  = 72.0 MB
  u16* w1b = (u16*)(ws + (size_t)0x5E00000);    // 64 MB
  u16* w2b = (u16*)(ws + (size_t)0x9E00000);    // 64 MB  (total ~222 MB)

  zero_kernel<<<1, 64, 0, stream>>>(counts);
  gate_kernel<<<N_TOK / 4, 256, 0, stream>>>(x, gw, gb, expert_id, counts);
  scan_kernel<<<1, 64, 0, stream>>>(counts, offs, cursor);
  gather_kernel<<<N_TOK, 256, 0, stream>>>(x, expert_id, offs, cursor, perm, xg);
  wconv_kernel<<<dim3(DIM / 64, HID / 64, NEXP), 256, 0, stream>>>(w1, w1b, DIM, HID);
  wconv_kernel<<<dim3(HID / 64, DIM / 64, NEXP), 256, 0, stream>>>(w2, w2b, HID, DIM);
  gemm1_kernel<<<dim3(HID / 128, N_TOK / 128, NEXP), 256, 0, stream>>>(
      xg, w1b, b1, counts, offs, h);
  gemm2_kernel<<<dim3(DIM / 128, N_TOK / 128, NEXP), 256, 0, stream>>>(
      h, w2b, b2, x, counts, offs, perm, out);
}

// Round 3
// 790.988 us; speedup vs baseline: 1.1484x; 1.1484x over previous
//
#include <hip/hip_runtime.h>
#include <hip/hip_bf16.h>
#include <stdint.h>

#define N_TOK 8192
#define DIM   1024
#define NEXP  8
#define HID   4096
#define MT_MAX 72                        // 9216/128 padded m-tiles
#define NWG1 (NEXP * MT_MAX * (HID/128)) // 18432
#define NWG2 (NEXP * MT_MAX * (DIM/128)) // 4608

typedef unsigned short u16;
typedef __attribute__((ext_vector_type(8))) short bf16x8;
typedef __attribute__((ext_vector_type(4))) float f32x4;

__device__ inline u16 f2bf(float f) {
  union { float f; uint32_t u; } v; v.f = f;
  uint32_t r = v.u + 0x7fffu + ((v.u >> 16) & 1u);
  return (u16)(r >> 16);
}

__device__ inline void gld_lds16(const void* g, void* lds) {
  __builtin_amdgcn_global_load_lds(
      (const __attribute__((address_space(1))) uint32_t*)g,
      (__attribute__((address_space(3))) uint32_t*)lds, 16, 0, 0);
}

// ---------------- small kernels ----------------

__global__ void zero_kernel(int* counts) {
  if (threadIdx.x < NEXP) counts[threadIdx.x] = 0;
}

__global__ void gate_kernel(const float* __restrict__ x,
                            const float* __restrict__ gw,
                            const float* __restrict__ gb,
                            int* __restrict__ expert_id,
                            int* __restrict__ counts) {
  int wave = threadIdx.x >> 6;
  int lane = threadIdx.x & 63;
  int n = blockIdx.x * 4 + wave;
  const float* xr = x + (size_t)n * DIM;
  float acc[8];
#pragma unroll
  for (int e = 0; e < 8; ++e) acc[e] = 0.f;
  for (int d = lane; d < DIM; d += 64) {
    float xv = xr[d];
    const float4 g0 = *(const float4*)&gw[d * 8];
    const float4 g1 = *(const float4*)&gw[d * 8 + 4];
    acc[0] += xv * g0.x; acc[1] += xv * g0.y;
    acc[2] += xv * g0.z; acc[3] += xv * g0.w;
    acc[4] += xv * g1.x; acc[5] += xv * g1.y;
    acc[6] += xv * g1.z; acc[7] += xv * g1.w;
  }
#pragma unroll
  for (int e = 0; e < 8; ++e)
    for (int off = 32; off > 0; off >>= 1)
      acc[e] += __shfl_xor(acc[e], off);
  if (lane == 0) {
    float best = acc[0] + gb[0];
    int bi = 0;
#pragma unroll
    for (int e = 1; e < 8; ++e) {
      float v = acc[e] + gb[e];
      if (v > best) { best = v; bi = e; }
    }
    expert_id[n] = bi;
    atomicAdd(&counts[bi], 1);
  }
}

__global__ void scan_kernel(const int* __restrict__ counts,
                            int* __restrict__ offs,
                            int* __restrict__ cursor) {
  if (threadIdx.x == 0) {
    int o = 0;
    for (int e = 0; e < NEXP; ++e) {
      offs[e] = o;
      o += (counts[e] + 127) & ~127;
      cursor[e] = 0;
    }
    offs[NEXP] = o;
  }
}

__global__ void gather_kernel(const float* __restrict__ x,
                              const int* __restrict__ expert_id,
                              const int* __restrict__ offs,
                              int* __restrict__ cursor,
                              int* __restrict__ perm,
                              u16* __restrict__ xg) {
  int n = blockIdx.x;
  __shared__ int spos;
  if (threadIdx.x == 0) {
    int e = expert_id[n];
    int p = offs[e] + atomicAdd(&cursor[e], 1);
    perm[p] = n;
    spos = p;
  }
  __syncthreads();
  int pos = spos;
  int i = threadIdx.x * 4;
  const float4 v = *(const float4*)&x[(size_t)n * DIM + i];
  ushort4 o;
  o.x = f2bf(v.x); o.y = f2bf(v.y); o.z = f2bf(v.z); o.w = f2bf(v.w);
  *(ushort4*)&xg[(size_t)pos * DIM + i] = o;
}

// src: [E][K][Nc] fp32 -> dst: [E][Nc][K] bf16 (transposed)
__global__ void wconv_kernel(const float* __restrict__ src,
                             u16* __restrict__ dst, int K, int Nc) {
  int e = blockIdx.z;
  int kb = blockIdx.x * 64;
  int nb = blockIdx.y * 64;
  const float* s = src + (size_t)e * K * Nc;
  u16* d = dst + (size_t)e * K * Nc;
  __shared__ __align__(16) u16 tile[64][68];   // 136B row stride: 8B-aligned, bank-spread
  int rr = threadIdx.x >> 4;
  int cc = (threadIdx.x & 15) * 4;
#pragma unroll
  for (int p = 0; p < 4; ++p) {
    int row = p * 16 + rr;
    const float4 v = *(const float4*)&s[(size_t)(kb + row) * Nc + nb + cc];
    ushort4 t;
    t.x = f2bf(v.x); t.y = f2bf(v.y); t.z = f2bf(v.z); t.w = f2bf(v.w);
    *(ushort4*)&tile[row][cc] = t;
  }
  __syncthreads();
#pragma unroll
  for (int p = 0; p < 4; ++p) {
    int n = p * 16 + rr;
    ushort4 o;
    o.x = tile[cc + 0][n];
    o.y = tile[cc + 1][n];
    o.z = tile[cc + 2][n];
    o.w = tile[cc + 3][n];
    *(ushort4*)&d[(size_t)(nb + n) * K + kb + cc] = o;
  }
}

// ------- GEMM core: 128x128 tile, BK=64, 4 waves, dbuf+prefetch, XOR-swizzled LDS -------
// LDS[r][c] = G[r][c ^ (r&7)] (chunks of 8 u16): linear gld_lds dest + permuted
// per-lane global source chunk; ds_read applies the same XOR (rule #21 both-sides).

template<int K>
__device__ __forceinline__ void gemm_core(const u16* __restrict__ Ab,
                                          const u16* __restrict__ Bb,
                                          f32x4 acc[4][4], u16* sm) {
  const int tid = threadIdx.x;
  const int wave = tid >> 6, lane = tid & 63;
  const int wr = (wave >> 1) * 64, wc = (wave & 1) * 64;
  const int l15 = lane & 15, l4 = lane >> 4;
  const int srow = lane >> 3;                    // 0..7
  const int schunk = ((lane & 7) ^ srow) * 8;    // inverse-swizzled source col (u16)

  u16* A0 = sm;          u16* B0 = sm + 8192;
  u16* A1 = sm + 16384;  u16* B1 = sm + 24576;

  auto STAGE = [&](u16* Ad, u16* Bd, int kk) {
#pragma unroll
    for (int j = 0; j < 4; ++j) {
      int r0 = j * 32 + wave * 8;
      gld_lds16(Ab + (size_t)(r0 + srow) * K + kk + schunk, Ad + r0 * 64);
      gld_lds16(Bb + (size_t)(r0 + srow) * K + kk + schunk, Bd + r0 * 64);
    }
  };
  auto COMPUTE = [&](const u16* As, const u16* Bs) {
#pragma unroll
    for (int ks = 0; ks < 2; ++ks) {
      bf16x8 a[4], b[4];
#pragma unroll
      for (int i = 0; i < 4; ++i) {
        int r = wr + i * 16 + l15;
        a[i] = *(const bf16x8*)&As[r * 64 + ((ks * 32 + l4 * 8) ^ ((r & 7) * 8))];
      }
#pragma unroll
      for (int i = 0; i < 4; ++i) {
        int r = wc + i * 16 + l15;
        b[i] = *(const bf16x8*)&Bs[r * 64 + ((ks * 32 + l4 * 8) ^ ((r & 7) * 8))];
      }
#pragma unroll
      for (int mi = 0; mi < 4; ++mi)
#pragma unroll
        for (int ni = 0; ni < 4; ++ni)
          acc[mi][ni] = __builtin_amdgcn_mfma_f32_16x16x32_bf16(
              a[mi], b[ni], acc[mi][ni], 0, 0, 0);
    }
  };

  constexpr int NST = K / 64;   // 16 or 64, even
  STAGE(A0, B0, 0);
#pragma unroll 1
  for (int kt = 0; kt < NST - 2; kt += 2) {
    __syncthreads();
    STAGE(A1, B1, (kt + 1) * 64);   // prefetch overlaps COMPUTE below
    COMPUTE(A0, B0);
    __syncthreads();
    STAGE(A0, B0, (kt + 2) * 64);
    COMPUTE(A1, B1);
  }
  __syncthreads();
  STAGE(A1, B1, (NST - 1) * 64);
  COMPUTE(A0, B0);
  __syncthreads();
  COMPUTE(A1, B1);
}

__global__ __launch_bounds__(256, 2) void gemm1_kernel(
    const u16* __restrict__ xg, const u16* __restrict__ w1b,
    const float* __restrict__ b1, const int* __restrict__ counts,
    const int* __restrict__ offs, u16* __restrict__ h) {
  int fid = (int)(blockIdx.x & 7) * (NWG1 / 8) + (int)(blockIdx.x >> 3);  // XCD chunking
  int e = fid / (MT_MAX * 32);
  int rm = fid % (MT_MAX * 32);
  int mt = rm / 32, nt = rm % 32;
  int ne = counts[e];
  if (mt * 128 >= ne) return;
  int seg = offs[e];
  __shared__ __align__(16) u16 sm[32768];
  f32x4 acc[4][4];
#pragma unroll
  for (int i = 0; i < 4; ++i)
#pragma unroll
    for (int j = 0; j < 4; ++j) acc[i][j] = (f32x4){0.f, 0.f, 0.f, 0.f};

  const u16* Abase = xg + (size_t)(seg + mt * 128) * DIM;
  const u16* Bbase = w1b + ((size_t)e * HID + nt * 128) * DIM;
  gemm_core<DIM>(Abase, Bbase, acc, sm);

  const int tid = threadIdx.x;
  const int wave = tid >> 6, lane = tid & 63;
  const int wr = (wave >> 1) * 64, wc = (wave & 1) * 64;
  const int l15 = lane & 15, l4 = lane >> 4;
  const int rowlim = ne - mt * 128;
  const size_t hrow0 = (size_t)(seg + mt * 128);
#pragma unroll
  for (int mi = 0; mi < 4; ++mi)
#pragma unroll
    for (int j = 0; j < 4; ++j) {
      int r = wr + mi * 16 + l4 * 4 + j;
      if (r < rowlim) {
        u16* hp = h + (hrow0 + r) * (size_t)HID;
#pragma unroll
        for (int ni = 0; ni < 4; ++ni) {
          int c = nt * 128 + wc + ni * 16 + l15;
          float v = acc[mi][ni][j] + b1[e * HID + c];
          hp[c] = f2bf(fmaxf(v, 0.f));
        }
      }
    }
}

__global__ __launch_bounds__(256, 2) void gemm2_kernel(
    const u16* __restrict__ h, const u16* __restrict__ w2b,
    const float* __restrict__ b2, const float* __restrict__ x,
    const int* __restrict__ counts, const int* __restrict__ offs,
    const int* __restrict__ perm, float* __restrict__ out) {
  int fid = (int)(blockIdx.x & 7) * (NWG2 / 8) + (int)(blockIdx.x >> 3);
  int e = fid / (MT_MAX * 8);
  int rm = fid % (MT_MAX * 8);
  int mt = rm / 8, nt = rm % 8;
  int ne = counts[e];
  if (mt * 128 >= ne) return;
  int seg = offs[e];
  __shared__ __align__(16) u16 sm[32768];
  f32x4 acc[4][4];
#pragma unroll
  for (int i = 0; i < 4; ++i)
#pragma unroll
    for (int j = 0; j < 4; ++j) acc[i][j] = (f32x4){0.f, 0.f, 0.f, 0.f};

  const u16* Abase = h + (size_t)(seg + mt * 128) * HID;
  const u16* Bbase = w2b + ((size_t)e * DIM + nt * 128) * HID;
  gemm_core<HID>(Abase, Bbase, acc, sm);

  const int tid = threadIdx.x;
  const int wave = tid >> 6, lane = tid & 63;
  const int wr = (wave >> 1) * 64, wc = (wave & 1) * 64;
  const int l15 = lane & 15, l4 = lane >> 4;
  const int rowlim = ne - mt * 128;
  const int prow0 = seg + mt * 128;
#pragma unroll
  for (int mi = 0; mi < 4; ++mi)
#pragma unroll
    for (int j = 0; j < 4; ++j) {
      int r = wr + mi * 16 + l4 * 4 + j;
      if (r < rowlim) {
        int orig = perm[prow0 + r];
        const float* xr = x + (size_t)orig * DIM;
        float* op = out + (size_t)orig * DIM;
#pragma unroll
        for (int ni = 0; ni < 4; ++ni) {
          int c = nt * 128 + wc + ni * 16 + l15;
          op[c] = acc[mi][ni][j] + b2[e * DIM + c] + xr[c];
        }
      }
    }
}

// ---------------- launch ----------------

extern "C" void kernel_launch(void* const* d_in, const int* in_sizes, int n_in,
                              void* d_out, int out_size, void* d_ws, size_t ws_size,
                              hipStream_t stream) {
  const float* x  = (const float*)d_in[0];
  const float* gw = (const float*)d_in[1];
  const float* gb = (const float*)d_in[2];
  const float* w1 = (const float*)d_in[3];
  const float* b1 = (const float*)d_in[4];
  const float* w2 = (const float*)d_in[5];
  const float* b2 = (const float*)d_in[6];
  float* out = (float*)d_out;

  char* ws = (char*)d_ws;
  int* counts    = (int*)(ws + 0);
  int* offs      = (int*)(ws + 64);
  int* cursor    = (int*)(ws + 128);
  int* expert_id = (int*)(ws + 256);
  int* perm      = (int*)(ws + 33280);
  u16* xg  = (u16*)(ws + (size_t)131072);
  u16* h   = (u16*)(ws + (size_t)0x1400000);
  u16* w1b = (u16*)(ws + (size_t)0x5E00000);
  u16* w2b = (u16*)(ws + (size_t)0x9E00000);

  zero_kernel<<<1, 64, 0, stream>>>(counts);
  gate_kernel<<<N_TOK / 4, 256, 0, stream>>>(x, gw, gb, expert_id, counts);
  scan_kernel<<<1, 64, 0, stream>>>(counts, offs, cursor);
  gather_kernel<<<N_TOK, 256, 0, stream>>>(x, expert_id, offs, cursor, perm, xg);
  wconv_kernel<<<dim3(DIM / 64, HID / 64, NEXP), 256, 0, stream>>>(w1, w1b, DIM, HID);
  wconv_kernel<<<dim3(HID / 64, DIM / 64, NEXP), 256, 0, stream>>>(w2, w2b, HID, DIM);
  gemm1_kernel<<<NWG1, 256, 0, stream>>>(xg, w1b, b1, counts, offs, h);
  gemm2_kernel<<<NWG2, 256, 0, stream>>>(h, w2b, b2, x, counts, offs, perm, out);
}